// Round 1
// baseline (248.787 us; speedup 1.0000x reference)
//
#include <hip/hip_runtime.h>

#define NN 8192
#define DD 128
#define MARGINF 1.0f
#define LDSS 136   // 128 + 8 bf16 pad: keeps 16B alignment, balanced banks for ds_read_b128

typedef __attribute__((ext_vector_type(8))) short bf16x8;
typedef __attribute__((ext_vector_type(4))) float f32x4;

// ---------------- K0: fp32 -> bf16 (RNE) convert ----------------
__device__ __forceinline__ unsigned short f2bf(float x) {
    unsigned u = __float_as_uint(x);
    u = (u + 0x7FFFu + ((u >> 16) & 1u)) >> 16;
    return (unsigned short)u;
}

__global__ __launch_bounds__(256) void ml_convert_kernel(
    const float* __restrict__ a, const float* __restrict__ b,
    unsigned short* __restrict__ abf, unsigned short* __restrict__ bbf)
{
    int t = blockIdx.x * 256 + threadIdx.x;       // 0 .. 524287 (2 * 1M/4)
    const float* src = a;
    unsigned short* dst = abf;
    int idx = t;
    if (t >= 262144) { src = b; dst = bbf; idx = t - 262144; }
    float4 v = ((const float4*)src)[idx];
    ushort4 o;
    o.x = f2bf(v.x); o.y = f2bf(v.y); o.z = f2bf(v.z); o.w = f2bf(v.w);
    ((ushort4*)dst)[idx] = o;
}

// ---------------- K1: fused GEMM + masked exp + row-sum -> V ----------------
// Block tile 128x128, 4 waves in 2x2, each wave 4x4 grid of 16x16x32 bf16 MFMA.
// A frag: lane holds A[m=lane&15][k=(lane>>4)*8+j]; B frag symmetric (row of b = col of B).
// C/D: col = lane&15, row = (lane>>4)*4 + reg.
__global__ __launch_bounds__(256, 2) void ml_vsum_gemm_kernel(
    const unsigned short* __restrict__ abf, const unsigned short* __restrict__ bbf,
    const int* __restrict__ labels, float* __restrict__ V)
{
    __shared__ unsigned short As[128 * LDSS];
    __shared__ unsigned short Bs[128 * LDSS];
    __shared__ int labI[128];
    __shared__ int labJ[128];

    const int tid  = threadIdx.x;
    const int row0 = blockIdx.y * 128;
    const int col0 = blockIdx.x * 128;

    // Stage A,B tiles: 128 rows x 128 bf16 each; 16 chunks of 16B per row.
#pragma unroll
    for (int it = 0; it < 8; it++) {
        int c = tid + it * 256;              // 0..2047
        int r = c >> 4, ch = c & 15;
        *(uint4*)(&As[r * LDSS + ch * 8]) = *(const uint4*)(&abf[(row0 + r) * DD + ch * 8]);
    }
#pragma unroll
    for (int it = 0; it < 8; it++) {
        int c = tid + it * 256;
        int r = c >> 4, ch = c & 15;
        *(uint4*)(&Bs[r * LDSS + ch * 8]) = *(const uint4*)(&bbf[(col0 + r) * DD + ch * 8]);
    }
    if (tid < 128) labI[tid] = labels[row0 + tid];
    else           labJ[tid - 128] = labels[col0 + tid - 128];
    __syncthreads();

    const int lane = tid & 63;
    const int wave = tid >> 6;
    const int wi = (wave >> 1) * 64;     // wave row offset within tile
    const int wj = (wave & 1) * 64;      // wave col offset within tile
    const int m  = lane & 15;
    const int q  = lane >> 4;

    f32x4 acc[4][4];
    f32x4 zero = {0.f, 0.f, 0.f, 0.f};
#pragma unroll
    for (int ti = 0; ti < 4; ti++)
#pragma unroll
        for (int tj = 0; tj < 4; tj++) acc[ti][tj] = zero;

#pragma unroll
    for (int k0 = 0; k0 < DD; k0 += 32) {
        const int kk = k0 + q * 8;
        bf16x8 af[4], bfr[4];
#pragma unroll
        for (int ti = 0; ti < 4; ti++)
            af[ti] = *(const bf16x8*)(&As[(wi + ti * 16 + m) * LDSS + kk]);
#pragma unroll
        for (int tj = 0; tj < 4; tj++)
            bfr[tj] = *(const bf16x8*)(&Bs[(wj + tj * 16 + m) * LDSS + kk]);
#pragma unroll
        for (int ti = 0; ti < 4; ti++)
#pragma unroll
            for (int tj = 0; tj < 4; tj++)
                acc[ti][tj] = __builtin_amdgcn_mfma_f32_16x16x32_bf16(af[ti], bfr[tj], acc[ti][tj], 0, 0, 0);
    }

    // Epilogue: exp(margin + S) where labels differ, reduce over cols, atomicAdd into V.
#pragma unroll
    for (int ti = 0; ti < 4; ti++) {
        const int li_base = wi + ti * 16 + q * 4;
        const int l0 = labI[li_base + 0], l1 = labI[li_base + 1];
        const int l2 = labI[li_base + 2], l3 = labI[li_base + 3];
        float rs0 = 0.f, rs1 = 0.f, rs2 = 0.f, rs3 = 0.f;
#pragma unroll
        for (int tj = 0; tj < 4; tj++) {
            const int labj = labJ[wj + tj * 16 + m];
            f32x4 c = acc[ti][tj];
            rs0 += (l0 != labj) ? __expf(MARGINF + c[0]) : 0.f;
            rs1 += (l1 != labj) ? __expf(MARGINF + c[1]) : 0.f;
            rs2 += (l2 != labj) ? __expf(MARGINF + c[2]) : 0.f;
            rs3 += (l3 != labj) ? __expf(MARGINF + c[3]) : 0.f;
        }
#pragma unroll
        for (int off = 1; off < 16; off <<= 1) {
            rs0 += __shfl_xor(rs0, off);
            rs1 += __shfl_xor(rs1, off);
            rs2 += __shfl_xor(rs2, off);
            rs3 += __shfl_xor(rs3, off);
        }
        if (m == 0) {
            atomicAdd(&V[row0 + li_base + 0], rs0);
            atomicAdd(&V[row0 + li_base + 1], rs1);
            atomicAdd(&V[row0 + li_base + 2], rs2);
            atomicAdd(&V[row0 + li_base + 3], rs3);
        }
    }
}

// ---------------- K2: positive pairs, exact fp32 S_ij, hinge^2 sum ----------------
__global__ __launch_bounds__(256) void ml_pospair_kernel(
    const float* __restrict__ a, const float* __restrict__ b,
    const int* __restrict__ labels, const float* __restrict__ V,
    double* __restrict__ loss_sum, int* __restrict__ num_pos)
{
    __shared__ int   labS[NN];        // 32 KB
    __shared__ float aS[8 * DD];      // 4 KB
    __shared__ float ps[4];
    __shared__ int   cs[4];

    const int tid = threadIdx.x;
    const int i0  = blockIdx.x * 8;

    for (int j = tid; j < NN; j += 256) labS[j] = labels[j];
    ((float4*)aS)[tid] = ((const float4*)(a + i0 * DD))[tid];   // 8 rows = 256 float4
    __syncthreads();

    float partial = 0.f;
    int   cnt = 0;
#pragma unroll 1
    for (int ii = 0; ii < 8; ii++) {
        const int i = i0 + ii;
        const int labi = labS[i];
        const float Vi = V[i];
        const float4* arow = (const float4*)(aS + ii * DD);
        for (int j = tid; j < NN; j += 256) {
            if (labS[j] == labi && j != i) {
                const float4* brow = (const float4*)(b + j * DD);
                float s = 0.f;
#pragma unroll
                for (int k = 0; k < 32; k++) {
                    float4 av = arow[k];
                    float4 bv = brow[k];
                    s = fmaf(av.x, bv.x, fmaf(av.y, bv.y, fmaf(av.z, bv.z, fmaf(av.w, bv.w, s))));
                }
                float h = fmaxf(logf(Vi + V[j]) - s, 0.f);
                partial += h * h;
                cnt++;
            }
        }
    }
    // block reduce (4 waves)
    for (int off = 32; off > 0; off >>= 1) {
        partial += __shfl_down(partial, off);
        cnt     += __shfl_down(cnt, off);
    }
    const int lane = tid & 63, w = tid >> 6;
    if (lane == 0) { ps[w] = partial; cs[w] = cnt; }
    __syncthreads();
    if (tid == 0) {
        float  tot = ps[0] + ps[1] + ps[2] + ps[3];
        int    c   = cs[0] + cs[1] + cs[2] + cs[3];
        atomicAdd(loss_sum, (double)tot);
        atomicAdd(num_pos, c);
    }
}

// ---------------- K3: finalize ----------------
__global__ void ml_finalize_kernel(const double* __restrict__ loss_sum,
                                   const int* __restrict__ num_pos,
                                   float* __restrict__ out)
{
    out[0] = (float)(loss_sum[0] / (2.0 * (double)num_pos[0]));
}

// ---------------- launch ----------------
extern "C" void kernel_launch(void* const* d_in, const int* in_sizes, int n_in,
                              void* d_out, int out_size, void* d_ws, size_t ws_size,
                              hipStream_t stream)
{
    const float* a      = (const float*)d_in[0];
    const float* b      = (const float*)d_in[1];
    const int*   labels = (const int*)d_in[2];
    float* out = (float*)d_out;

    char* ws = (char*)d_ws;
    // ws layout: [0, 2MB) a_bf16 | [2MB, 4MB) b_bf16 | [4MB, +32KB) V | loss_sum(double) | num_pos(int)
    unsigned short* abf = (unsigned short*)ws;
    unsigned short* bbf = (unsigned short*)(ws + 2097152);
    float*  V        = (float*)(ws + 4194304);
    double* loss_sum = (double*)(ws + 4227072);
    int*    num_pos  = (int*)(ws + 4227080);

    // zero V + accumulators (ws is re-poisoned to 0xAA before every launch)
    hipMemsetAsync(ws + 4194304, 0, 32768 + 16, stream);

    ml_convert_kernel<<<2048, 256, 0, stream>>>(a, b, abf, bbf);

    dim3 g(NN / 128, NN / 128);
    ml_vsum_gemm_kernel<<<g, 256, 0, stream>>>(abf, bbf, labels, V);

    ml_pospair_kernel<<<NN / 8, 256, 0, stream>>>(a, b, labels, V, loss_sum, num_pos);

    ml_finalize_kernel<<<1, 1, 0, stream>>>(loss_sum, num_pos, out);
}

// Round 2
// 190.275 us; speedup vs baseline: 1.3075x; 1.3075x over previous
//
#include <hip/hip_runtime.h>

#define NN 8192
#define DD 128
#define MARGINF 1.0f
#define LDSS 136   // 128 + 8 bf16 pad: keeps 16B alignment, 2-way bank alias (free) for ds_read_b128
#define MAXCLS 64  // max members per class; Binom(8192,1/1024) mean 8 -> P(>64) astronomically small

typedef __attribute__((ext_vector_type(8))) short bf16x8;
typedef __attribute__((ext_vector_type(4))) float f32x4;

// ---------------- K0: fp32 -> bf16 (RNE) convert ----------------
__device__ __forceinline__ unsigned short f2bf(float x) {
    unsigned u = __float_as_uint(x);
    u = (u + 0x7FFFu + ((u >> 16) & 1u)) >> 16;
    return (unsigned short)u;
}

__global__ __launch_bounds__(256) void ml_convert_kernel(
    const float* __restrict__ a, const float* __restrict__ b,
    unsigned short* __restrict__ abf, unsigned short* __restrict__ bbf)
{
    int t = blockIdx.x * 256 + threadIdx.x;       // 0 .. 524287 (2 * 1M/4)
    const float* src = a;
    unsigned short* dst = abf;
    int idx = t;
    if (t >= 262144) { src = b; dst = bbf; idx = t - 262144; }
    float4 v = ((const float4*)src)[idx];
    ushort4 o;
    o.x = f2bf(v.x); o.y = f2bf(v.y); o.z = f2bf(v.z); o.w = f2bf(v.w);
    ((ushort4*)dst)[idx] = o;
}

// ---------------- K1: fused GEMM + masked exp + row-sum -> V ----------------
// Block tile 128x128, 4 waves in 2x2, each wave 4x4 grid of 16x16x32 bf16 MFMA.
// C/D layout: col = lane&15, row = (lane>>4)*4 + reg  [learn_hip m89/m91]
__global__ __launch_bounds__(256, 2) void ml_vsum_gemm_kernel(
    const unsigned short* __restrict__ abf, const unsigned short* __restrict__ bbf,
    const int* __restrict__ labels, float* __restrict__ V)
{
    __shared__ unsigned short As[128 * LDSS];
    __shared__ unsigned short Bs[128 * LDSS];
    __shared__ int labI[128];
    __shared__ int labJ[128];

    const int tid  = threadIdx.x;
    const int row0 = blockIdx.y * 128;
    const int col0 = blockIdx.x * 128;

#pragma unroll
    for (int it = 0; it < 8; it++) {
        int c = tid + it * 256;              // 0..2047
        int r = c >> 4, ch = c & 15;
        *(uint4*)(&As[r * LDSS + ch * 8]) = *(const uint4*)(&abf[(row0 + r) * DD + ch * 8]);
    }
#pragma unroll
    for (int it = 0; it < 8; it++) {
        int c = tid + it * 256;
        int r = c >> 4, ch = c & 15;
        *(uint4*)(&Bs[r * LDSS + ch * 8]) = *(const uint4*)(&bbf[(col0 + r) * DD + ch * 8]);
    }
    if (tid < 128) labI[tid] = labels[row0 + tid];
    else           labJ[tid - 128] = labels[col0 + tid - 128];
    __syncthreads();

    const int lane = tid & 63;
    const int wave = tid >> 6;
    const int wi = (wave >> 1) * 64;
    const int wj = (wave & 1) * 64;
    const int m  = lane & 15;
    const int q  = lane >> 4;

    f32x4 acc[4][4];
    f32x4 zero = {0.f, 0.f, 0.f, 0.f};
#pragma unroll
    for (int ti = 0; ti < 4; ti++)
#pragma unroll
        for (int tj = 0; tj < 4; tj++) acc[ti][tj] = zero;

#pragma unroll
    for (int k0 = 0; k0 < DD; k0 += 32) {
        const int kk = k0 + q * 8;
        bf16x8 af[4], bfr[4];
#pragma unroll
        for (int ti = 0; ti < 4; ti++)
            af[ti] = *(const bf16x8*)(&As[(wi + ti * 16 + m) * LDSS + kk]);
#pragma unroll
        for (int tj = 0; tj < 4; tj++)
            bfr[tj] = *(const bf16x8*)(&Bs[(wj + tj * 16 + m) * LDSS + kk]);
#pragma unroll
        for (int ti = 0; ti < 4; ti++)
#pragma unroll
            for (int tj = 0; tj < 4; tj++)
                acc[ti][tj] = __builtin_amdgcn_mfma_f32_16x16x32_bf16(af[ti], bfr[tj], acc[ti][tj], 0, 0, 0);
    }

    // Epilogue: exp(margin + S) where labels differ, reduce over cols, atomicAdd into V.
    int labj[4];
#pragma unroll
    for (int tj = 0; tj < 4; tj++) labj[tj] = labJ[wj + tj * 16 + m];  // hoisted: 4 LDS reads, not 16

#pragma unroll
    for (int ti = 0; ti < 4; ti++) {
        const int li_base = wi + ti * 16 + q * 4;
        const int l0 = labI[li_base + 0], l1 = labI[li_base + 1];
        const int l2 = labI[li_base + 2], l3 = labI[li_base + 3];
        float rs0 = 0.f, rs1 = 0.f, rs2 = 0.f, rs3 = 0.f;
#pragma unroll
        for (int tj = 0; tj < 4; tj++) {
            f32x4 c = acc[ti][tj];
            rs0 += (l0 != labj[tj]) ? __expf(MARGINF + c[0]) : 0.f;
            rs1 += (l1 != labj[tj]) ? __expf(MARGINF + c[1]) : 0.f;
            rs2 += (l2 != labj[tj]) ? __expf(MARGINF + c[2]) : 0.f;
            rs3 += (l3 != labj[tj]) ? __expf(MARGINF + c[3]) : 0.f;
        }
#pragma unroll
        for (int off = 1; off < 16; off <<= 1) {
            rs0 += __shfl_xor(rs0, off);
            rs1 += __shfl_xor(rs1, off);
            rs2 += __shfl_xor(rs2, off);
            rs3 += __shfl_xor(rs3, off);
        }
        if (m == 0) {
            atomicAdd(&V[row0 + li_base + 0], rs0);
            atomicAdd(&V[row0 + li_base + 1], rs1);
            atomicAdd(&V[row0 + li_base + 2], rs2);
            atomicAdd(&V[row0 + li_base + 3], rs3);
        }
    }
}

// ---------------- K2a: bucket rows by class ----------------
__global__ __launch_bounds__(256) void ml_bucket_kernel(
    const int* __restrict__ labels, int* __restrict__ cnt, int* __restrict__ list)
{
    int t = blockIdx.x * 256 + threadIdx.x;   // 0..8191
    int c = labels[t];
    int p = atomicAdd(&cnt[c], 1);
    if (p < MAXCLS) list[c * MAXCLS + p] = t;
}

// ---------------- K2b: one block per class; exact fp32 dots on positive pairs ----------------
__global__ __launch_bounds__(64) void ml_pairs_kernel(
    const float* __restrict__ a, const float* __restrict__ b,
    const int* __restrict__ cnt, const int* __restrict__ list,
    const float* __restrict__ V,
    double* __restrict__ loss_sum, int* __restrict__ num_pos)
{
    __shared__ int   mem[MAXCLS];
    __shared__ float vS[MAXCLS];

    const int c   = blockIdx.x;
    const int tid = threadIdx.x;
    int mc = cnt[c];
    if (mc > MAXCLS) mc = MAXCLS;
    if (tid < mc) {
        int r = list[c * MAXCLS + tid];
        mem[tid] = r;
        vS[tid]  = V[r];
    }
    __syncthreads();

    const int pairs = mc * (mc - 1);          // ordered pairs i != j
    const int g = tid >> 4;                   // 4 groups of 16 lanes
    const int l = tid & 15;
    float partial = 0.f;
    int   count   = 0;

    for (int p = g; p < pairs; p += 4) {
        int i  = p / (mc - 1);
        int jj = p - i * (mc - 1);
        int j  = jj + (jj >= i);
        int ri = mem[i], rj = mem[j];
        const float4* ar = (const float4*)(a + ri * DD) + l * 2;
        const float4* br = (const float4*)(b + rj * DD) + l * 2;
        float4 a0 = ar[0], a1 = ar[1];
        float4 b0 = br[0], b1 = br[1];
        float s = 0.f;
        s = fmaf(a0.x, b0.x, s); s = fmaf(a0.y, b0.y, s);
        s = fmaf(a0.z, b0.z, s); s = fmaf(a0.w, b0.w, s);
        s = fmaf(a1.x, b1.x, s); s = fmaf(a1.y, b1.y, s);
        s = fmaf(a1.z, b1.z, s); s = fmaf(a1.w, b1.w, s);
        s += __shfl_xor(s, 1);
        s += __shfl_xor(s, 2);
        s += __shfl_xor(s, 4);
        s += __shfl_xor(s, 8);
        if (l == 0) {
            float h = fmaxf(logf(vS[i] + vS[j]) - s, 0.f);
            partial += h * h;
            count++;
        }
    }
    // reduce across the single 64-lane wave
    for (int off = 32; off > 0; off >>= 1) {
        partial += __shfl_down(partial, off);
        count   += __shfl_down(count, off);
    }
    if (tid == 0) {
        atomicAdd(loss_sum, (double)partial);
        atomicAdd(num_pos, count);
    }
}

// ---------------- K3: finalize ----------------
__global__ void ml_finalize_kernel(const double* __restrict__ loss_sum,
                                   const int* __restrict__ num_pos,
                                   float* __restrict__ out)
{
    out[0] = (float)(loss_sum[0] / (2.0 * (double)num_pos[0]));
}

// ---------------- launch ----------------
extern "C" void kernel_launch(void* const* d_in, const int* in_sizes, int n_in,
                              void* d_out, int out_size, void* d_ws, size_t ws_size,
                              hipStream_t stream)
{
    const float* a      = (const float*)d_in[0];
    const float* b      = (const float*)d_in[1];
    const int*   labels = (const int*)d_in[2];
    float* out = (float*)d_out;

    char* ws = (char*)d_ws;
    // ws layout:
    //   [0, 2MB)        a_bf16
    //   [2MB, 4MB)      b_bf16
    //   base2 = 4MB:
    //     +0      V[8192] f32            (32768 B)
    //     +32768  loss_sum (double)      (8 B)
    //     +32776  num_pos (int)          (4 B) + pad
    //     +32784  cnt[1024] int          (4096 B)
    //     +36880  list[1024*64] int      (262144 B)
    unsigned short* abf = (unsigned short*)ws;
    unsigned short* bbf = (unsigned short*)(ws + 2097152);
    char*   base2    = ws + 4194304;
    float*  V        = (float*)(base2);
    double* loss_sum = (double*)(base2 + 32768);
    int*    num_pos  = (int*)(base2 + 32776);
    int*    cnt      = (int*)(base2 + 32784);
    int*    list     = (int*)(base2 + 36880);

    // zero V + accumulators + cnt (ws is re-poisoned to 0xAA before every launch)
    hipMemsetAsync(base2, 0, 36880, stream);

    ml_convert_kernel<<<2048, 256, 0, stream>>>(a, b, abf, bbf);

    dim3 g(NN / 128, NN / 128);
    ml_vsum_gemm_kernel<<<g, 256, 0, stream>>>(abf, bbf, labels, V);

    ml_bucket_kernel<<<NN / 256, 256, 0, stream>>>(labels, cnt, list);

    ml_pairs_kernel<<<1024, 64, 0, stream>>>(a, b, cnt, list, V, loss_sum, num_pos);

    ml_finalize_kernel<<<1, 1, 0, stream>>>(loss_sum, num_pos, out);
}

// Round 4
// 138.985 us; speedup vs baseline: 1.7900x; 1.3690x over previous
//
#include <hip/hip_runtime.h>

#define NN 8192
#define DD 128
#define MARGINF 1.0f
#define MAXCLS 64   // max members per class; Binom(8192,1/1024) mean 8 -> P(>64) negligible
#define NCHUNK 8    // j-chunks; grid = NCHUNK x 64 = 512 blocks = 2/CU

typedef __attribute__((ext_vector_type(8))) short bf16x8;
typedef __attribute__((ext_vector_type(4))) float f32x4;

// async global->LDS 16B: lane L's 16B lands at (wave-uniform) lptr + L*16
__device__ __forceinline__ void load16_lds(const unsigned short* g, unsigned short* l) {
    __builtin_amdgcn_global_load_lds(
        (const __attribute__((address_space(1))) unsigned int*)g,
        (__attribute__((address_space(3))) unsigned int*)l,
        16, 0, 0);
}

// ---------------- K0: fp32 -> bf16 (RNE) convert + class bucketing ----------------
__device__ __forceinline__ unsigned short f2bf(float x) {
    unsigned u = __float_as_uint(x);
    u = (u + 0x7FFFu + ((u >> 16) & 1u)) >> 16;
    return (unsigned short)u;
}

__global__ __launch_bounds__(256) void ml_convert_kernel(
    const float* __restrict__ a, const float* __restrict__ b,
    const int* __restrict__ labels,
    unsigned short* __restrict__ abf, unsigned short* __restrict__ bbf,
    int* __restrict__ cnt, int* __restrict__ list)
{
    int t = blockIdx.x * 256 + threadIdx.x;       // 0 .. 524287
    const float* src = a;
    unsigned short* dst = abf;
    int idx = t;
    if (t >= 262144) { src = b; dst = bbf; idx = t - 262144; }
    float4 v = ((const float4*)src)[idx];
    ushort4 o;
    o.x = f2bf(v.x); o.y = f2bf(v.y); o.z = f2bf(v.z); o.w = f2bf(v.w);
    ((ushort4*)dst)[idx] = o;

    if (t < NN) {   // fused bucket append (cnt pre-zeroed by memset)
        int c = labels[t];
        int p = atomicAdd(&cnt[c], 1);
        if (p < MAXCLS) list[c * MAXCLS + p] = t;
    }
}

// ---------------- K1: flash-style fused GEMM + masked exp + V partials ----------------
// grid (NCHUNK, 64). Block: 128-row stripe x 1024-col chunk, 256 thr (4 waves 2x2).
// A-tile staged once, A-fragments register-resident; loop 8 B-tiles.
// LDS layout swizzled: row r, 16B-chunk c stored at pos (c ^ (r&7)) -> linear for
// global_load_lds DMA AND conflict-free ds_read_b128 (8 lanes per 4-bank group).
// MFMA 16x16x32 bf16: A[m=lane&15][k=(lane>>4)*8+j]; C/D col=lane&15, row=(lane>>4)*4+reg.
// R4 fix: waves sharing a row-half (wj=0 / wj=64) combine V partials via LDS
// before the store — R3 raced plain stores and dropped half the columns.
__global__ __launch_bounds__(256, 2) void ml_vsum_gemm_kernel(
    const unsigned short* __restrict__ abf, const unsigned short* __restrict__ bbf,
    const int* __restrict__ labels, float* __restrict__ Vp)
{
    __shared__ unsigned short As[128 * DD];   // 32 KB, no pad (DMA-linear)
    __shared__ unsigned short Bs[128 * DD];   // 32 KB
    __shared__ int labI[128];
    __shared__ int labJ[128];
    __shared__ float red[2][64];              // cross-wave V combine

    const int tid  = threadIdx.x;
    const int lane = tid & 63;
    const int wv   = tid >> 6;
    const int row0 = blockIdx.y * 128;
    const int chunk = blockIdx.x;

    const int lr = lane >> 4;      // staging: row-within-4
    const int p  = lane & 15;      // staging: slot
    const int m  = lane & 15;      // mfma row/col lane
    const int q  = lane >> 4;
    const int xr = m & 7;          // read-side swizzle key

    // ---- stage A (once) + B(jt=0) + labels ----
#pragma unroll
    for (int i = 0; i < 8; i++) {
        int rb = wv * 32 + i * 4;
        int r  = rb + lr;
        int c  = p ^ (r & 7);
        load16_lds(&abf[(size_t)(row0 + r) * DD + c * 8], &As[rb * DD]);
    }
    {
        int j0 = chunk * 1024;
#pragma unroll
        for (int i = 0; i < 8; i++) {
            int rb = wv * 32 + i * 4;
            int r  = rb + lr;
            int c  = p ^ (r & 7);
            load16_lds(&bbf[(size_t)(j0 + r) * DD + c * 8], &Bs[rb * DD]);
        }
        if (tid < 128) labI[tid] = labels[row0 + tid];
        else           labJ[tid - 128] = labels[j0 + tid - 128];
    }
    __syncthreads();

    const int wi = (wv >> 1) * 64;
    const int wj = (wv & 1) * 64;

    // ---- A fragments -> registers (read once) ----
    bf16x8 afr[4][4];
#pragma unroll
    for (int ti = 0; ti < 4; ti++)
#pragma unroll
        for (int ks = 0; ks < 4; ks++) {
            int r   = wi + ti * 16 + m;
            int pos = (ks * 4 + q) ^ xr;
            afr[ti][ks] = *(const bf16x8*)(&As[r * DD + pos * 8]);
        }

    int li[4][4];
#pragma unroll
    for (int ti = 0; ti < 4; ti++)
#pragma unroll
        for (int rg = 0; rg < 4; rg++)
            li[ti][rg] = labI[wi + ti * 16 + q * 4 + rg];

    float rs[4][4];
#pragma unroll
    for (int ti = 0; ti < 4; ti++)
#pragma unroll
        for (int rg = 0; rg < 4; rg++) rs[ti][rg] = 0.f;

    const f32x4 zero = {0.f, 0.f, 0.f, 0.f};

    // ---- j-tile loop ----
#pragma unroll 1
    for (int jt = 0; jt < 8; jt++) {
        f32x4 acc[4][4];
#pragma unroll
        for (int ti = 0; ti < 4; ti++)
#pragma unroll
            for (int tj = 0; tj < 4; tj++) acc[ti][tj] = zero;

#pragma unroll
        for (int ks = 0; ks < 4; ks++) {
            bf16x8 bfr[4];
#pragma unroll
            for (int tj = 0; tj < 4; tj++) {
                int r   = wj + tj * 16 + m;
                int pos = (ks * 4 + q) ^ xr;
                bfr[tj] = *(const bf16x8*)(&Bs[r * DD + pos * 8]);
            }
#pragma unroll
            for (int ti = 0; ti < 4; ti++)
#pragma unroll
                for (int tj = 0; tj < 4; tj++)
                    acc[ti][tj] = __builtin_amdgcn_mfma_f32_16x16x32_bf16(afr[ti][ks], bfr[tj], acc[ti][tj], 0, 0, 0);
        }

        // epilogue: masked exp accumulate into register partials (no reduce yet)
        int labj[4];
#pragma unroll
        for (int tj = 0; tj < 4; tj++) labj[tj] = labJ[wj + tj * 16 + m];
#pragma unroll
        for (int ti = 0; ti < 4; ti++)
#pragma unroll
            for (int tj = 0; tj < 4; tj++) {
                f32x4 c = acc[ti][tj];
                rs[ti][0] += (li[ti][0] != labj[tj]) ? __expf(MARGINF + c[0]) : 0.f;
                rs[ti][1] += (li[ti][1] != labj[tj]) ? __expf(MARGINF + c[1]) : 0.f;
                rs[ti][2] += (li[ti][2] != labj[tj]) ? __expf(MARGINF + c[2]) : 0.f;
                rs[ti][3] += (li[ti][3] != labj[tj]) ? __expf(MARGINF + c[3]) : 0.f;
            }

        __syncthreads();   // all B reads done
        if (jt < 7) {
            int j0 = chunk * 1024 + (jt + 1) * 128;
#pragma unroll
            for (int i = 0; i < 8; i++) {
                int rb = wv * 32 + i * 4;
                int r  = rb + lr;
                int c  = p ^ (r & 7);
                load16_lds(&bbf[(size_t)(j0 + r) * DD + c * 8], &Bs[rb * DD]);
            }
            if (tid < 128) labJ[tid] = labels[j0 + tid];
        }
        __syncthreads();   // stage complete
    }

    // ---- reduce over the 16 col-lanes ----
#pragma unroll
    for (int ti = 0; ti < 4; ti++)
#pragma unroll
        for (int rg = 0; rg < 4; rg++) {
            float v = rs[ti][rg];
            v += __shfl_xor(v, 1);
            v += __shfl_xor(v, 2);
            v += __shfl_xor(v, 4);
            v += __shfl_xor(v, 8);
            rs[ti][rg] = v;
        }

    // ---- cross-wave combine (wj=64 wave deposits; wj=0 wave adds + stores) ----
    if ((wv & 1) == 1 && m == 0) {
#pragma unroll
        for (int ti = 0; ti < 4; ti++)
#pragma unroll
            for (int rg = 0; rg < 4; rg++)
                red[wv >> 1][ti * 16 + q * 4 + rg] = rs[ti][rg];
    }
    __syncthreads();
    if ((wv & 1) == 0 && m == 0) {
#pragma unroll
        for (int ti = 0; ti < 4; ti++)
#pragma unroll
            for (int rg = 0; rg < 4; rg++) {
                int rloc = ti * 16 + q * 4 + rg;
                Vp[(size_t)chunk * NN + row0 + wi + rloc] = rs[ti][rg] + red[wv >> 1][rloc];
            }
    }
}

// ---------------- K2: positive pairs (exact fp32) + fused finalize ----------------
__global__ __launch_bounds__(256) void ml_pairs_kernel(
    const float* __restrict__ a, const float* __restrict__ b,
    const int* __restrict__ cnt, const int* __restrict__ list,
    const float* __restrict__ Vp,
    double* __restrict__ loss_sum, int* __restrict__ num_pos,
    unsigned int* __restrict__ done, float* __restrict__ out)
{
    __shared__ int   mem[MAXCLS];
    __shared__ float vS[MAXCLS];
    __shared__ float ps[4];
    __shared__ int   cs[4];

    const int c   = blockIdx.x;
    const int tid = threadIdx.x;
    int mc = cnt[c];
    if (mc > MAXCLS) mc = MAXCLS;
    if (tid < mc) {
        int r = list[c * MAXCLS + tid];
        mem[tid] = r;
        float v = 0.f;
#pragma unroll
        for (int jc = 0; jc < NCHUNK; jc++) v += Vp[(size_t)jc * NN + r];
        vS[tid] = v;
    }
    __syncthreads();

    const int pairs = mc * (mc - 1);
    const int g = tid >> 4;                   // 16 groups of 16 lanes
    const int l = tid & 15;
    float partial = 0.f;
    int   count   = 0;

    for (int pp = g; pp < pairs; pp += 16) {
        int i  = pp / (mc - 1);
        int jj = pp - i * (mc - 1);
        int j  = jj + (jj >= i);
        int ri = mem[i], rj = mem[j];
        const float4* ar = (const float4*)(a + ri * DD) + l * 2;
        const float4* br = (const float4*)(b + rj * DD) + l * 2;
        float4 a0 = ar[0], a1 = ar[1];
        float4 b0 = br[0], b1 = br[1];
        float s = 0.f;
        s = fmaf(a0.x, b0.x, s); s = fmaf(a0.y, b0.y, s);
        s = fmaf(a0.z, b0.z, s); s = fmaf(a0.w, b0.w, s);
        s = fmaf(a1.x, b1.x, s); s = fmaf(a1.y, b1.y, s);
        s = fmaf(a1.z, b1.z, s); s = fmaf(a1.w, b1.w, s);
        s += __shfl_xor(s, 1);
        s += __shfl_xor(s, 2);
        s += __shfl_xor(s, 4);
        s += __shfl_xor(s, 8);
        if (l == 0) {
            float h = fmaxf(logf(vS[i] + vS[j]) - s, 0.f);
            partial += h * h;
            count++;
        }
    }
    // wave reduce, then cross-wave via LDS
    for (int off = 32; off > 0; off >>= 1) {
        partial += __shfl_down(partial, off);
        count   += __shfl_down(count, off);
    }
    const int lane = tid & 63, wv = tid >> 6;
    if (lane == 0) { ps[wv] = partial; cs[wv] = count; }
    __syncthreads();
    if (tid == 0) {
        float tot = ps[0] + ps[1] + ps[2] + ps[3];
        int   ct  = cs[0] + cs[1] + cs[2] + cs[3];
        atomicAdd(loss_sum, (double)tot);
        atomicAdd(num_pos, ct);
        __threadfence();
        unsigned d = atomicAdd(done, 1u);
        if (d == 1023u) {                      // last block finalizes
            double ls = atomicAdd(loss_sum, 0.0);   // device-scope coherent read
            int    np = atomicAdd(num_pos, 0);
            out[0] = (float)(ls / (2.0 * (double)np));
        }
    }
}

// ---------------- launch ----------------
extern "C" void kernel_launch(void* const* d_in, const int* in_sizes, int n_in,
                              void* d_out, int out_size, void* d_ws, size_t ws_size,
                              hipStream_t stream)
{
    const float* a      = (const float*)d_in[0];
    const float* b      = (const float*)d_in[1];
    const int*   labels = (const int*)d_in[2];
    float* out = (float*)d_out;

    char* ws = (char*)d_ws;
    // ws layout:
    //   [0, 2MB)   a_bf16        [2MB, 4MB)  b_bf16
    //   base2 = 4MB:
    //     +0       cnt[1024]            4096 B   (memset 0)
    //     +4096    loss_sum (double)       8 B   (memset 0)
    //     +4104    num_pos (int)           4 B   (memset 0)
    //     +4108    done (uint)             4 B   (memset 0)
    //     +8192    list[1024*64]        256 KB
    //     +270336  V_part[8*8192] f32   256 KB
    unsigned short* abf = (unsigned short*)ws;
    unsigned short* bbf = (unsigned short*)(ws + 2097152);
    char*    base2    = ws + 4194304;
    int*     cnt      = (int*)(base2);
    double*  loss_sum = (double*)(base2 + 4096);
    int*     num_pos  = (int*)(base2 + 4104);
    unsigned* done    = (unsigned*)(base2 + 4108);
    int*     list     = (int*)(base2 + 8192);
    float*   Vp       = (float*)(base2 + 270336);

    hipMemsetAsync(base2, 0, 4112, stream);

    ml_convert_kernel<<<2048, 256, 0, stream>>>(a, b, labels, abf, bbf, cnt, list);

    dim3 g(NCHUNK, NN / 128);
    ml_vsum_gemm_kernel<<<g, 256, 0, stream>>>(abf, bbf, labels, Vp);

    ml_pairs_kernel<<<1024, 256, 0, stream>>>(a, b, cnt, list, Vp, loss_sum, num_pos, done, out);
}

// Round 5
// 122.217 us; speedup vs baseline: 2.0356x; 1.1372x over previous
//
#include <hip/hip_runtime.h>

#define NN 8192
#define DD 128
#define MARGINF 1.0f
#define MAXCLS 64   // max members per class; Binom(8192,1/1024) mean 8 -> P(>64) negligible
#define NCHUNK 8    // j-chunks; grid = NCHUNK x 64 = 512 blocks = 2/CU
#define LOG2E 1.4426950408889634f
#define E1    2.718281828459045f   // e^margin, margin = 1

typedef __attribute__((ext_vector_type(8))) short bf16x8;
typedef __attribute__((ext_vector_type(4))) float f32x4;

// async global->LDS 16B: lane L's 16B lands at (wave-uniform) lptr + L*16
__device__ __forceinline__ void load16_lds(const unsigned short* g, unsigned short* l) {
    __builtin_amdgcn_global_load_lds(
        (const __attribute__((address_space(1))) unsigned int*)g,
        (__attribute__((address_space(3))) unsigned int*)l,
        16, 0, 0);
}

// ---------------- K0: fp32 -> bf16 (RNE) convert + class bucketing ----------------
// A-half is pre-scaled by log2(e) so the GEMM epilogue needs only exp2 (1 hw op).
__device__ __forceinline__ unsigned short f2bf(float x) {
    unsigned u = __float_as_uint(x);
    u = (u + 0x7FFFu + ((u >> 16) & 1u)) >> 16;
    return (unsigned short)u;
}

__global__ __launch_bounds__(256) void ml_convert_kernel(
    const float* __restrict__ a, const float* __restrict__ b,
    const int* __restrict__ labels,
    unsigned short* __restrict__ abf, unsigned short* __restrict__ bbf,
    int* __restrict__ cnt, int* __restrict__ list)
{
    int t = blockIdx.x * 256 + threadIdx.x;       // 0 .. 524287
    const float* src = a;
    unsigned short* dst = abf;
    int idx = t;
    float scale = LOG2E;                           // A rows carry the log2e factor
    if (t >= 262144) { src = b; dst = bbf; idx = t - 262144; scale = 1.0f; }
    float4 v = ((const float4*)src)[idx];
    ushort4 o;
    o.x = f2bf(v.x * scale); o.y = f2bf(v.y * scale);
    o.z = f2bf(v.z * scale); o.w = f2bf(v.w * scale);
    ((ushort4*)dst)[idx] = o;

    if (t < NN) {   // fused bucket append (cnt pre-zeroed by memset)
        int c = labels[t];
        int p = atomicAdd(&cnt[c], 1);
        if (p < MAXCLS) list[c * MAXCLS + p] = t;
    }
}

// ---------------- K1: flash-style GEMM + unmasked exp2 row-sum -> Vp partials ----------------
// grid (NCHUNK, 64). Block: 128-row stripe x 1024-col chunk, 256 thr (4 waves 2x2).
// A staged once (fragments register-resident); loop 8 B-tiles via global_load_lds w=16.
// LDS swizzle: row r, 16B-chunk c at pos (c ^ (r&7)) -> DMA-linear AND conflict-free b128 reads.
// Epilogue: rs += exp2(acc) over ALL columns (no label mask — positives subtracted in K2).
// Vp stores raw sum of exp(S); the e^margin factor is applied in K2.
__global__ __launch_bounds__(256, 2) void ml_vsum_gemm_kernel(
    const unsigned short* __restrict__ abf, const unsigned short* __restrict__ bbf,
    float* __restrict__ Vp)
{
    __shared__ unsigned short As[128 * DD];   // 32 KB, no pad (DMA-linear)
    __shared__ unsigned short Bs[128 * DD];   // 32 KB
    __shared__ float red[2][64];              // cross-wave V combine

    const int tid  = threadIdx.x;
    const int lane = tid & 63;
    const int wv   = tid >> 6;
    const int row0 = blockIdx.y * 128;
    const int chunk = blockIdx.x;

    const int lr = lane >> 4;      // staging: row-within-4
    const int p  = lane & 15;      // staging: slot
    const int m  = lane & 15;      // mfma row/col lane
    const int q  = lane >> 4;
    const int xr = m & 7;          // read-side swizzle key

    // ---- stage A (once) + B(jt=0) ----
#pragma unroll
    for (int i = 0; i < 8; i++) {
        int rb = wv * 32 + i * 4;
        int r  = rb + lr;
        int c  = p ^ (r & 7);
        load16_lds(&abf[(size_t)(row0 + r) * DD + c * 8], &As[rb * DD]);
    }
    {
        int j0 = chunk * 1024;
#pragma unroll
        for (int i = 0; i < 8; i++) {
            int rb = wv * 32 + i * 4;
            int r  = rb + lr;
            int c  = p ^ (r & 7);
            load16_lds(&bbf[(size_t)(j0 + r) * DD + c * 8], &Bs[rb * DD]);
        }
    }
    __syncthreads();

    const int wi = (wv >> 1) * 64;
    const int wj = (wv & 1) * 64;

    // ---- A fragments -> registers (read once) ----
    bf16x8 afr[4][4];
#pragma unroll
    for (int ti = 0; ti < 4; ti++)
#pragma unroll
        for (int ks = 0; ks < 4; ks++) {
            int r   = wi + ti * 16 + m;
            int pos = (ks * 4 + q) ^ xr;
            afr[ti][ks] = *(const bf16x8*)(&As[r * DD + pos * 8]);
        }

    float rs[4][4];
#pragma unroll
    for (int ti = 0; ti < 4; ti++)
#pragma unroll
        for (int rg = 0; rg < 4; rg++) rs[ti][rg] = 0.f;

    const f32x4 zero = {0.f, 0.f, 0.f, 0.f};

    // ---- j-tile loop ----
#pragma unroll 1
    for (int jt = 0; jt < 8; jt++) {
        f32x4 acc[4][4];
#pragma unroll
        for (int ti = 0; ti < 4; ti++)
#pragma unroll
            for (int tj = 0; tj < 4; tj++) acc[ti][tj] = zero;

#pragma unroll
        for (int ks = 0; ks < 4; ks++) {
            bf16x8 bfr[4];
#pragma unroll
            for (int tj = 0; tj < 4; tj++) {
                int r   = wj + tj * 16 + m;
                int pos = (ks * 4 + q) ^ xr;
                bfr[tj] = *(const bf16x8*)(&Bs[r * DD + pos * 8]);
            }
#pragma unroll
            for (int ti = 0; ti < 4; ti++)
#pragma unroll
                for (int tj = 0; tj < 4; tj++)
                    acc[ti][tj] = __builtin_amdgcn_mfma_f32_16x16x32_bf16(afr[ti][ks], bfr[tj], acc[ti][tj], 0, 0, 0);
        }

        // epilogue: unmasked exp2 accumulate (A pre-scaled by log2e -> exp2(acc)=exp(S))
#pragma unroll
        for (int ti = 0; ti < 4; ti++)
#pragma unroll
            for (int tj = 0; tj < 4; tj++) {
                f32x4 c = acc[ti][tj];
                rs[ti][0] += exp2f(c[0]);
                rs[ti][1] += exp2f(c[1]);
                rs[ti][2] += exp2f(c[2]);
                rs[ti][3] += exp2f(c[3]);
            }

        __syncthreads();   // all B reads done
        if (jt < 7) {
            int j0 = chunk * 1024 + (jt + 1) * 128;
#pragma unroll
            for (int i = 0; i < 8; i++) {
                int rb = wv * 32 + i * 4;
                int r  = rb + lr;
                int c  = p ^ (r & 7);
                load16_lds(&bbf[(size_t)(j0 + r) * DD + c * 8], &Bs[rb * DD]);
            }
        }
        __syncthreads();   // stage complete
    }

    // ---- reduce over the 16 col-lanes ----
#pragma unroll
    for (int ti = 0; ti < 4; ti++)
#pragma unroll
        for (int rg = 0; rg < 4; rg++) {
            float v = rs[ti][rg];
            v += __shfl_xor(v, 1);
            v += __shfl_xor(v, 2);
            v += __shfl_xor(v, 4);
            v += __shfl_xor(v, 8);
            rs[ti][rg] = v;
        }

    // ---- cross-wave combine (wj=64 wave deposits; wj=0 wave adds + stores) ----
    if ((wv & 1) == 1 && m == 0) {
#pragma unroll
        for (int ti = 0; ti < 4; ti++)
#pragma unroll
            for (int rg = 0; rg < 4; rg++)
                red[wv >> 1][ti * 16 + q * 4 + rg] = rs[ti][rg];
    }
    __syncthreads();
    if ((wv & 1) == 0 && m == 0) {
#pragma unroll
        for (int ti = 0; ti < 4; ti++)
#pragma unroll
            for (int rg = 0; rg < 4; rg++) {
                int rloc = ti * 16 + q * 4 + rg;
                Vp[(size_t)chunk * NN + row0 + wi + rloc] = rs[ti][rg] + red[wv >> 1][rloc];
            }
    }
}

// ---------------- K2: per-class exact fp32 dots, V-adjust, hinge^2; slot writes ----------------
// Phase 1: all mc^2 ordered (i,j) incl. diagonal -> S cached in LDS, exp-sums per i.
// V_adj[i] = e^margin * (sum_all exp(S) - sum_sameclass exp(S))  == reference V[i].
// Phase 2: one thread per ordered pair i!=j: hinge from cached S. No same-address atomics:
// per-class slots + last-done-block reduce (R4's 46us pairs kernel was ~3K serialized
// same-address device atomics).
__global__ __launch_bounds__(256) void ml_pairs_kernel(
    const float* __restrict__ a, const float* __restrict__ b,
    const int* __restrict__ cnt, const int* __restrict__ list,
    const float* __restrict__ Vp,
    float* __restrict__ classLoss, int* __restrict__ classCnt,
    unsigned int* __restrict__ done, float* __restrict__ out)
{
    __shared__ int   mem[MAXCLS];
    __shared__ float sumExp[MAXCLS];
    __shared__ float Vadj[MAXCLS];
    __shared__ float Sc[MAXCLS * MAXCLS];   // 16 KB
    __shared__ float ps[4];
    __shared__ int   cs[4];
    __shared__ double dred[4];
    __shared__ long long cred[4];

    const int c   = blockIdx.x;
    const int tid = threadIdx.x;
    int mc = cnt[c];
    if (mc > MAXCLS) mc = MAXCLS;

    float vsum = 0.f;
    if (tid < mc) {
        int r = list[c * MAXCLS + tid];
        mem[tid] = r;
#pragma unroll
        for (int jc = 0; jc < NCHUNK; jc++) vsum += Vp[(size_t)jc * NN + r];
    }
    if (tid < MAXCLS) sumExp[tid] = 0.f;
    __syncthreads();

    // ---- phase 1: mc^2 dots (16-lane groups), cache S, accumulate exp sums ----
    const int g = tid >> 4;                   // 16 groups
    const int l = tid & 15;
    const int tot1 = mc * mc;
    for (int pp = g; pp < tot1; pp += 16) {
        int i = pp / mc;
        int j = pp - i * mc;
        int ri = mem[i], rj = mem[j];
        const float4* ar = (const float4*)(a + (size_t)ri * DD) + l * 2;
        const float4* br = (const float4*)(b + (size_t)rj * DD) + l * 2;
        float4 a0 = ar[0], a1 = ar[1];
        float4 b0 = br[0], b1 = br[1];
        float s = 0.f;
        s = fmaf(a0.x, b0.x, s); s = fmaf(a0.y, b0.y, s);
        s = fmaf(a0.z, b0.z, s); s = fmaf(a0.w, b0.w, s);
        s = fmaf(a1.x, b1.x, s); s = fmaf(a1.y, b1.y, s);
        s = fmaf(a1.z, b1.z, s); s = fmaf(a1.w, b1.w, s);
        s += __shfl_xor(s, 1);
        s += __shfl_xor(s, 2);
        s += __shfl_xor(s, 4);
        s += __shfl_xor(s, 8);
        if (l == 0) {
            Sc[i * MAXCLS + j] = s;
            atomicAdd(&sumExp[i], __expf(s));
        }
    }
    __syncthreads();

    if (tid < mc) Vadj[tid] = E1 * (vsum - sumExp[tid]);
    __syncthreads();

    // ---- phase 2: one thread per ordered pair (i != j) ----
    float partial = 0.f;
    int   count   = 0;
    for (int pp = tid; pp < tot1; pp += 256) {
        int i = pp / mc;
        int j = pp - i * mc;
        if (i != j) {
            float h = fmaxf(logf(Vadj[i] + Vadj[j]) - Sc[i * MAXCLS + j], 0.f);
            partial += h * h;
            count++;
        }
    }
    for (int off = 32; off > 0; off >>= 1) {
        partial += __shfl_down(partial, off);
        count   += __shfl_down(count, off);
    }
    const int lane = tid & 63, wv = tid >> 6;
    if (lane == 0) { ps[wv] = partial; cs[wv] = count; }
    __syncthreads();

    if (tid == 0) {
        float tot = ps[0] + ps[1] + ps[2] + ps[3];
        int   ct  = cs[0] + cs[1] + cs[2] + cs[3];
        atomicExch(&classLoss[c], tot);   // device-scope visible slot writes
        atomicExch(&classCnt[c], ct);
    }
    __syncthreads();

    // ---- last block reduces the 1024 class slots ----
    if (tid == 0) ps[0] = (float)atomicAdd(done, 1u);
    __syncthreads();
    if ((unsigned)ps[0] == 1023u) {
        double dls = 0.0;
        long long dct = 0;
        for (int k = tid; k < 1024; k += 256) {
            dls += (double)atomicAdd(&classLoss[k], 0.0f);   // coherent reads
            dct += (long long)atomicAdd(&classCnt[k], 0);
        }
        for (int off = 32; off > 0; off >>= 1) {
            dls += __shfl_down(dls, off);
            dct += __shfl_down(dct, off);
        }
        if (lane == 0) { dred[wv] = dls; cred[wv] = dct; }
        __syncthreads();
        if (tid == 0) {
            double ls = dred[0] + dred[1] + dred[2] + dred[3];
            long long np = cred[0] + cred[1] + cred[2] + cred[3];
            out[0] = (float)(ls / (2.0 * (double)np));
        }
    }
}

// ---------------- launch ----------------
extern "C" void kernel_launch(void* const* d_in, const int* in_sizes, int n_in,
                              void* d_out, int out_size, void* d_ws, size_t ws_size,
                              hipStream_t stream)
{
    const float* a      = (const float*)d_in[0];
    const float* b      = (const float*)d_in[1];
    const int*   labels = (const int*)d_in[2];
    float* out = (float*)d_out;

    char* ws = (char*)d_ws;
    // ws layout:
    //   [0, 2MB)   a_bf16 (scaled by log2e)    [2MB, 4MB)  b_bf16
    //   base2 = 4MB:
    //     +0       cnt[1024]            4096 B   (memset 0)
    //     +4096    done (uint)             4 B   (memset 0)
    //     +8192    classLoss[1024] f32  4096 B   (written unconditionally)
    //     +12288   classCnt[1024] int   4096 B
    //     +16384   list[1024*64]        256 KB
    //     +278528  Vp[8*8192] f32       256 KB
    unsigned short* abf = (unsigned short*)ws;
    unsigned short* bbf = (unsigned short*)(ws + 2097152);
    char*     base2     = ws + 4194304;
    int*      cnt       = (int*)(base2);
    unsigned* done      = (unsigned*)(base2 + 4096);
    float*    classLoss = (float*)(base2 + 8192);
    int*      classCnt  = (int*)(base2 + 12288);
    int*      list      = (int*)(base2 + 16384);
    float*    Vp        = (float*)(base2 + 278528);

    hipMemsetAsync(base2, 0, 4100, stream);

    ml_convert_kernel<<<2048, 256, 0, stream>>>(a, b, labels, abf, bbf, cnt, list);

    dim3 g(NCHUNK, NN / 128);
    ml_vsum_gemm_kernel<<<g, 256, 0, stream>>>(abf, bbf, Vp);

    ml_pairs_kernel<<<1024, 256, 0, stream>>>(a, b, cnt, list, Vp, classLoss, classCnt, done, out);
}

// Round 6
// 113.638 us; speedup vs baseline: 2.1893x; 1.0755x over previous
//
#include <hip/hip_runtime.h>

#define NN 8192
#define DD 128
#define MARGINF 1.0f
#define MAXCLS 64   // max members per class; Binom(8192,1/1024) mean 8 -> P(>64) negligible
#define NCHUNK 8    // j-chunks; grid = NCHUNK x 64 = 512 blocks = 2/CU
#define LOG2E 1.4426950408889634f
#define E1    2.718281828459045f   // e^margin, margin = 1

typedef __attribute__((ext_vector_type(8))) short bf16x8;
typedef __attribute__((ext_vector_type(4))) float f32x4;

#if __has_builtin(__builtin_amdgcn_exp2f)
#define EXP2F(x) __builtin_amdgcn_exp2f(x)
#else
#define EXP2F(x) exp2f(x)
#endif

// async global->LDS 16B: lane L's 16B lands at (wave-uniform) lptr + L*16
__device__ __forceinline__ void load16_lds(const unsigned short* g, unsigned short* l) {
    __builtin_amdgcn_global_load_lds(
        (const __attribute__((address_space(1))) unsigned int*)g,
        (__attribute__((address_space(3))) unsigned int*)l,
        16, 0, 0);
}

// ---------------- K0: fp32 -> bf16 (RNE) convert + class bucketing ----------------
__device__ __forceinline__ unsigned short f2bf(float x) {
    unsigned u = __float_as_uint(x);
    u = (u + 0x7FFFu + ((u >> 16) & 1u)) >> 16;
    return (unsigned short)u;
}

__global__ __launch_bounds__(256) void ml_convert_kernel(
    const float* __restrict__ a, const float* __restrict__ b,
    const int* __restrict__ labels,
    unsigned short* __restrict__ abf, unsigned short* __restrict__ bbf,
    int* __restrict__ cnt, int* __restrict__ list)
{
    int t = blockIdx.x * 256 + threadIdx.x;       // 0 .. 524287
    const float* src = a;
    unsigned short* dst = abf;
    int idx = t;
    float scale = LOG2E;                           // A rows carry the log2e factor
    if (t >= 262144) { src = b; dst = bbf; idx = t - 262144; scale = 1.0f; }
    float4 v = ((const float4*)src)[idx];
    ushort4 o;
    o.x = f2bf(v.x * scale); o.y = f2bf(v.y * scale);
    o.z = f2bf(v.z * scale); o.w = f2bf(v.w * scale);
    ((ushort4*)dst)[idx] = o;

    if (t < NN) {   // fused bucket append (cnt pre-zeroed by memset)
        int c = labels[t];
        int p = atomicAdd(&cnt[c], 1);
        if (p < MAXCLS) list[c * MAXCLS + p] = t;
    }
}

// ---------------- K1: flash-style GEMM + unmasked exp2 row-sum -> Vp partials ----------------
// grid (NCHUNK, 64). Block: 128-row stripe x 1024-col chunk, 256 thr (4 waves 2x2).
// A staged once (fragments register-resident); 16 B-tiles of 64 cols, DOUBLE-BUFFERED:
// per iter: compute buf[p] -> one __syncthreads (vmcnt drain lands ~1 tile after issue)
// -> issue tile jt+2 into buf[p]. Loads stay in flight across a full tile's compute.
// LDS swizzle: row r, 16B-chunk c at pos (c ^ (r&7)) -> DMA-linear AND conflict-free b128.
__global__ __launch_bounds__(256, 2) void ml_vsum_gemm_kernel(
    const unsigned short* __restrict__ abf, const unsigned short* __restrict__ bbf,
    float* __restrict__ Vp)
{
    __shared__ unsigned short As[128 * DD];       // 32 KB
    __shared__ unsigned short Bs[2][64 * DD];     // 2 x 16 KB
    __shared__ float red[2][64];                  // cross-wave V combine

    const int tid  = threadIdx.x;
    const int lane = tid & 63;
    const int wv   = tid >> 6;
    const int row0 = blockIdx.y * 128;
    const int j0   = blockIdx.x * 1024;

    const int lr = lane >> 4;      // staging: row-within-4
    const int p  = lane & 15;      // staging: slot
    const int m  = lane & 15;      // mfma row/col lane
    const int q  = lane >> 4;
    const int xr = m & 7;          // read-side swizzle key

    // ---- issue A (once) + B tiles 0,1 ----
#pragma unroll
    for (int i = 0; i < 8; i++) {
        int rb = wv * 32 + i * 4;
        int r  = rb + lr;
        int cc = p ^ (r & 7);
        load16_lds(&abf[(size_t)(row0 + r) * DD + cc * 8], &As[rb * DD]);
    }
#pragma unroll
    for (int i = 0; i < 4; i++) {
        int rb = wv * 16 + i * 4;
        int r  = rb + lr;
        int cc = p ^ (r & 7);
        load16_lds(&bbf[(size_t)(j0 + r) * DD + cc * 8], &Bs[0][rb * DD]);
    }
#pragma unroll
    for (int i = 0; i < 4; i++) {
        int rb = wv * 16 + i * 4;
        int r  = rb + lr;
        int cc = p ^ (r & 7);
        load16_lds(&bbf[(size_t)(j0 + 64 + r) * DD + cc * 8], &Bs[1][rb * DD]);
    }
    __syncthreads();

    const int wi = (wv >> 1) * 64;   // row-half
    const int wj = (wv & 1) * 32;    // col-half of the 64-col tile

    // ---- A fragments -> registers (read once) ----
    bf16x8 afr[4][4];
#pragma unroll
    for (int ti = 0; ti < 4; ti++)
#pragma unroll
        for (int ks = 0; ks < 4; ks++) {
            int r   = wi + ti * 16 + m;
            int pos = (ks * 4 + q) ^ xr;
            afr[ti][ks] = *(const bf16x8*)(&As[r * DD + pos * 8]);
        }

    float rs[4][4];
#pragma unroll
    for (int ti = 0; ti < 4; ti++)
#pragma unroll
        for (int rg = 0; rg < 4; rg++) rs[ti][rg] = 0.f;

    const f32x4 zero = {0.f, 0.f, 0.f, 0.f};

    // ---- j-tile loop: 16 tiles of 64 cols, double-buffered ----
#pragma unroll 2
    for (int jt = 0; jt < 16; jt++) {
        const int pb = jt & 1;
        f32x4 acc[4][2];
#pragma unroll
        for (int ti = 0; ti < 4; ti++)
#pragma unroll
            for (int tj = 0; tj < 2; tj++) acc[ti][tj] = zero;

#pragma unroll
        for (int ks = 0; ks < 4; ks++) {
            bf16x8 bfr[2];
#pragma unroll
            for (int tj = 0; tj < 2; tj++) {
                int r   = wj + tj * 16 + m;
                int pos = (ks * 4 + q) ^ xr;
                bfr[tj] = *(const bf16x8*)(&Bs[pb][r * DD + pos * 8]);
            }
#pragma unroll
            for (int ti = 0; ti < 4; ti++)
#pragma unroll
                for (int tj = 0; tj < 2; tj++)
                    acc[ti][tj] = __builtin_amdgcn_mfma_f32_16x16x32_bf16(afr[ti][ks], bfr[tj], acc[ti][tj], 0, 0, 0);
        }

        // epilogue: unmasked exp2 accumulate (A pre-scaled by log2e -> exp2(acc)=exp(S))
#pragma unroll
        for (int ti = 0; ti < 4; ti++)
#pragma unroll
            for (int tj = 0; tj < 2; tj++) {
                f32x4 c = acc[ti][tj];
                rs[ti][0] += EXP2F(c[0]);
                rs[ti][1] += EXP2F(c[1]);
                rs[ti][2] += EXP2F(c[2]);
                rs[ti][3] += EXP2F(c[3]);
            }

        __syncthreads();   // drains prefetch (issued ~1 tile ago) + all reads of buf[pb] done
        if (jt < 14) {
            int jb = j0 + (jt + 2) * 64;
#pragma unroll
            for (int i = 0; i < 4; i++) {
                int rb = wv * 16 + i * 4;
                int r  = rb + lr;
                int cc = p ^ (r & 7);
                load16_lds(&bbf[(size_t)(jb + r) * DD + cc * 8], &Bs[pb][rb * DD]);
            }
        }
    }

    // ---- reduce over the 16 col-lanes ----
#pragma unroll
    for (int ti = 0; ti < 4; ti++)
#pragma unroll
        for (int rg = 0; rg < 4; rg++) {
            float v = rs[ti][rg];
            v += __shfl_xor(v, 1);
            v += __shfl_xor(v, 2);
            v += __shfl_xor(v, 4);
            v += __shfl_xor(v, 8);
            rs[ti][rg] = v;
        }

    // ---- cross-wave combine (col-half waves deposit; col-base waves add + store) ----
    if ((wv & 1) == 1 && m == 0) {
#pragma unroll
        for (int ti = 0; ti < 4; ti++)
#pragma unroll
            for (int rg = 0; rg < 4; rg++)
                red[wv >> 1][ti * 16 + q * 4 + rg] = rs[ti][rg];
    }
    __syncthreads();
    if ((wv & 1) == 0 && m == 0) {
#pragma unroll
        for (int ti = 0; ti < 4; ti++)
#pragma unroll
            for (int rg = 0; rg < 4; rg++) {
                int rloc = ti * 16 + q * 4 + rg;
                Vp[(size_t)blockIdx.x * NN + row0 + wi + rloc] = rs[ti][rg] + red[wv >> 1][rloc];
            }
    }
}

// ---------------- K2: per-class exact fp32 dots, V-adjust, hinge^2; slot writes ----------------
__global__ __launch_bounds__(256) void ml_pairs_kernel(
    const float* __restrict__ a, const float* __restrict__ b,
    const int* __restrict__ cnt, const int* __restrict__ list,
    const float* __restrict__ Vp,
    float* __restrict__ classLoss, int* __restrict__ classCnt,
    unsigned int* __restrict__ done, float* __restrict__ out)
{
    __shared__ int   mem[MAXCLS];
    __shared__ float sumExp[MAXCLS];
    __shared__ float Vadj[MAXCLS];
    __shared__ float Sc[MAXCLS * MAXCLS];   // 16 KB
    __shared__ float ps[4];
    __shared__ int   cs[4];
    __shared__ double dred[4];
    __shared__ long long cred[4];

    const int c   = blockIdx.x;
    const int tid = threadIdx.x;
    int mc = cnt[c];
    if (mc > MAXCLS) mc = MAXCLS;

    float vsum = 0.f;
    if (tid < mc) {
        int r = list[c * MAXCLS + tid];
        mem[tid] = r;
#pragma unroll
        for (int jc = 0; jc < NCHUNK; jc++) vsum += Vp[(size_t)jc * NN + r];
    }
    if (tid < MAXCLS) sumExp[tid] = 0.f;
    __syncthreads();

    // ---- phase 1: mc^2 dots (16-lane groups), cache S, accumulate exp sums ----
    const int g = tid >> 4;                   // 16 groups
    const int l = tid & 15;
    const int tot1 = mc * mc;
    for (int pp = g; pp < tot1; pp += 16) {
        int i = pp / mc;
        int j = pp - i * mc;
        int ri = mem[i], rj = mem[j];
        const float4* ar = (const float4*)(a + (size_t)ri * DD) + l * 2;
        const float4* br = (const float4*)(b + (size_t)rj * DD) + l * 2;
        float4 a0 = ar[0], a1 = ar[1];
        float4 b0 = br[0], b1 = br[1];
        float s = 0.f;
        s = fmaf(a0.x, b0.x, s); s = fmaf(a0.y, b0.y, s);
        s = fmaf(a0.z, b0.z, s); s = fmaf(a0.w, b0.w, s);
        s = fmaf(a1.x, b1.x, s); s = fmaf(a1.y, b1.y, s);
        s = fmaf(a1.z, b1.z, s); s = fmaf(a1.w, b1.w, s);
        s += __shfl_xor(s, 1);
        s += __shfl_xor(s, 2);
        s += __shfl_xor(s, 4);
        s += __shfl_xor(s, 8);
        if (l == 0) {
            Sc[i * MAXCLS + j] = s;
            atomicAdd(&sumExp[i], __expf(s));
        }
    }
    __syncthreads();

    if (tid < mc) Vadj[tid] = E1 * (vsum - sumExp[tid]);
    __syncthreads();

    // ---- phase 2: one thread per ordered pair (i != j) ----
    float partial = 0.f;
    int   count   = 0;
    for (int pp = tid; pp < tot1; pp += 256) {
        int i = pp / mc;
        int j = pp - i * mc;
        if (i != j) {
            float h = fmaxf(logf(Vadj[i] + Vadj[j]) - Sc[i * MAXCLS + j], 0.f);
            partial += h * h;
            count++;
        }
    }
    for (int off = 32; off > 0; off >>= 1) {
        partial += __shfl_down(partial, off);
        count   += __shfl_down(count, off);
    }
    const int lane = tid & 63, wv = tid >> 6;
    if (lane == 0) { ps[wv] = partial; cs[wv] = count; }
    __syncthreads();

    if (tid == 0) {
        float tot = ps[0] + ps[1] + ps[2] + ps[3];
        int   ct  = cs[0] + cs[1] + cs[2] + cs[3];
        atomicExch(&classLoss[c], tot);   // device-scope visible slot writes
        atomicExch(&classCnt[c], ct);
    }
    __syncthreads();

    // ---- last block reduces the 1024 class slots ----
    if (tid == 0) ps[0] = (float)atomicAdd(done, 1u);
    __syncthreads();
    if ((unsigned)ps[0] == 1023u) {
        double dls = 0.0;
        long long dct = 0;
        for (int k = tid; k < 1024; k += 256) {
            dls += (double)atomicAdd(&classLoss[k], 0.0f);   // coherent reads
            dct += (long long)atomicAdd(&classCnt[k], 0);
        }
        for (int off = 32; off > 0; off >>= 1) {
            dls += __shfl_down(dls, off);
            dct += __shfl_down(dct, off);
        }
        if (lane == 0) { dred[wv] = dls; cred[wv] = dct; }
        __syncthreads();
        if (tid == 0) {
            double ls = dred[0] + dred[1] + dred[2] + dred[3];
            long long np = cred[0] + cred[1] + cred[2] + cred[3];
            out[0] = (float)(ls / (2.0 * (double)np));
        }
    }
}

// ---------------- launch ----------------
extern "C" void kernel_launch(void* const* d_in, const int* in_sizes, int n_in,
                              void* d_out, int out_size, void* d_ws, size_t ws_size,
                              hipStream_t stream)
{
    const float* a      = (const float*)d_in[0];
    const float* b      = (const float*)d_in[1];
    const int*   labels = (const int*)d_in[2];
    float* out = (float*)d_out;

    char* ws = (char*)d_ws;
    // ws layout:
    //   [0, 2MB)   a_bf16 (scaled by log2e)    [2MB, 4MB)  b_bf16
    //   base2 = 4MB:
    //     +0       cnt[1024]            4096 B   (memset 0)
    //     +4096    done (uint)             4 B   (memset 0)
    //     +8192    classLoss[1024] f32  4096 B   (written unconditionally)
    //     +12288   classCnt[1024] int   4096 B
    //     +16384   list[1024*64]        256 KB
    //     +278528  Vp[8*8192] f32       256 KB
    unsigned short* abf = (unsigned short*)ws;
    unsigned short* bbf = (unsigned short*)(ws + 2097152);
    char*     base2     = ws + 4194304;
    int*      cnt       = (int*)(base2);
    unsigned* done      = (unsigned*)(base2 + 4096);
    float*    classLoss = (float*)(base2 + 8192);
    int*      classCnt  = (int*)(base2 + 12288);
    int*      list      = (int*)(base2 + 16384);
    float*    Vp        = (float*)(base2 + 278528);

    hipMemsetAsync(base2, 0, 4100, stream);

    ml_convert_kernel<<<2048, 256, 0, stream>>>(a, b, labels, abf, bbf, cnt, list);

    dim3 g(NCHUNK, NN / 128);
    ml_vsum_gemm_kernel<<<g, 256, 0, stream>>>(abf, bbf, Vp);

    ml_pairs_kernel<<<1024, 256, 0, stream>>>(a, b, cnt, list, Vp, classLoss, classCnt, done, out);
}